// Round 1
// baseline (62.636 us; speedup 1.0000x reference)
//
#include <hip/hip_runtime.h>

#define NE 30
#define NB 2          // boxes per cell
#define NCELL (4096 * 196)
#define LAMBDA_COORD 5.0f
#define LAMBDA_NOOBJ 0.5f
#define EPSF 1e-12f

__global__ __launch_bounds__(256) void yolo_loss_kernel(
    const float* __restrict__ pred,
    const float* __restrict__ tgt,
    float* __restrict__ out)
{
    const int idx = blockIdx.x * blockDim.x + threadIdx.x;   // cell index
    float cell = 0.0f;

    if (idx < NCELL) {
        const float2* p2 = reinterpret_cast<const float2*>(pred + (size_t)idx * NE);
        const float2* t2 = reinterpret_cast<const float2*>(tgt  + (size_t)idx * NE);
        float p[NE], t[NE];
        #pragma unroll
        for (int k = 0; k < NE / 2; ++k) {
            float2 a = p2[k]; p[2*k] = a.x; p[2*k+1] = a.y;
            float2 b = t2[k]; t[2*k] = b.x; t[2*k+1] = b.y;
        }

        const float coord = (t[5] > 0.0f)  ? 1.0f : 0.0f;
        const float noobj = (t[5] == 0.0f) ? 1.0f : 0.0f;

        // class loss: indices 10..29
        float cls = 0.0f;
        #pragma unroll
        for (int k = NB * 5; k < NE; ++k) {
            float d = p[k] - t[k];
            cls += d * d;
        }
        cls *= coord;

        // confidence squared-diffs (used by both noobj and contain losses)
        float dconf0 = p[4] - t[4];
        float dconf1 = p[9] - t[9];
        float conf_sq0 = dconf0 * dconf0;
        float conf_sq1 = dconf1 * dconf1;
        float no = noobj * (conf_sq0 + conf_sq1);

        // corners + areas for both boxes of pred and target
        float c1[NB][4], c2[NB][4], a1[NB], a2[NB];
        #pragma unroll
        for (int i = 0; i < NB; ++i) {
            float x = p[i*5 + 0], y = p[i*5 + 1];
            float w2 = p[i*5 + 2] * p[i*5 + 2];
            float h2 = p[i*5 + 3] * p[i*5 + 3];
            c1[i][0] = x - w2; c1[i][1] = y - h2;
            c1[i][2] = x + w2; c1[i][3] = y + h2;
            a1[i] = (2.0f * w2) * (2.0f * h2);

            float tx = t[i*5 + 0], ty = t[i*5 + 1];
            float tw2 = t[i*5 + 2] * t[i*5 + 2];
            float th2 = t[i*5 + 3] * t[i*5 + 3];
            c2[i][0] = tx - tw2; c2[i][1] = ty - th2;
            c2[i][2] = tx + tw2; c2[i][3] = ty + th2;
            a2[i] = (2.0f * tw2) * (2.0f * th2);
        }

        // IoU matrix [pred i][tgt j]
        float iou[NB][NB];
        #pragma unroll
        for (int i = 0; i < NB; ++i) {
            #pragma unroll
            for (int j = 0; j < NB; ++j) {
                float tlx = fmaxf(c1[i][0], c2[j][0]);
                float tly = fmaxf(c1[i][1], c2[j][1]);
                float brx = fminf(c1[i][2], c2[j][2]);
                float bry = fminf(c1[i][3], c2[j][3]);
                float wx = fmaxf(brx - tlx, 0.0f);
                float wy = fmaxf(bry - tly, 0.0f);
                float inter = wx * wy;
                float uni = a1[i] + a2[j] - inter;
                iou[i][j] = inter / fmaxf(uni, EPSF);
            }
        }

        // argmax over pred axis, first-index tie-break:
        // max_idx[j] == 1  <=>  iou[1][j] > iou[0][j]  (strict)
        bool m0 = iou[1][0] > iou[0][0];   // max_idx for tgt box 0
        bool m1 = iou[1][1] > iou[0][1];   // max_idx for tgt box 1
        // resp[i] = any j with max_idx[j] == i
        float w0 = coord * ((!m0 || !m1) ? 1.0f : 0.0f);
        float w1 = coord * (( m0 ||  m1) ? 1.0f : 0.0f);

        // contain loss
        float contain = w0 * conf_sq0 + w1 * conf_sq1;

        // localization loss: coords 0..3 of each box
        float loc0 = 0.0f, loc1 = 0.0f;
        #pragma unroll
        for (int k = 0; k < 4; ++k) {
            float d0 = p[k] - t[k];
            float d1 = p[5 + k] - t[5 + k];
            loc0 += d0 * d0;
            loc1 += d1 * d1;
        }
        float loc = w0 * loc0 + w1 * loc1;

        cell = LAMBDA_COORD * loc + contain + LAMBDA_NOOBJ * no + cls;
    }

    // wave (64-lane) shuffle reduction
    #pragma unroll
    for (int off = 32; off > 0; off >>= 1)
        cell += __shfl_down(cell, off, 64);

    __shared__ float wsum[4];
    const int lane = threadIdx.x & 63;
    const int wid  = threadIdx.x >> 6;
    if (lane == 0) wsum[wid] = cell;
    __syncthreads();
    if (threadIdx.x == 0) {
        float s = wsum[0] + wsum[1] + wsum[2] + wsum[3];
        atomicAdd(out, s);
    }
}

extern "C" void kernel_launch(void* const* d_in, const int* in_sizes, int n_in,
                              void* d_out, int out_size, void* d_ws, size_t ws_size,
                              hipStream_t stream) {
    const float* pred = (const float*)d_in[0];
    const float* tgt  = (const float*)d_in[1];
    float* out = (float*)d_out;

    hipMemsetAsync(out, 0, sizeof(float) * out_size, stream);

    const int block = 256;
    const int grid = (NCELL + block - 1) / block;   // 3136
    hipLaunchKernelGGL(yolo_loss_kernel, dim3(grid), dim3(block), 0, stream,
                       pred, tgt, out);
}